// Round 15
// baseline (59.929 us; speedup 1.0000x reference)
//
#include <hip/hip_runtime.h>
#include <math.h>

// st_VQEmbedding, SINGLE fused kernel (no prep pass, no ws image).
// z [65536,64] f32, emb [512,64] f32 -> out = emb[argmin_k (x2-2dot)+e2],
// straight-through (q+x)-x. dot via bf16 2-term split MFMA (al*bh + ah*bl +
// ah*bh, fp32 accum) -- bit-identical chains/term order/tie-break to
// R5/R7/R8/R12/R13 (all passed absmax 0.0).
//
// R15: R7-R14 k-loop restructurings were all null at ~37us; the invariant
// was the prep->main two-kernel structure (launch drain + ws round-trip).
// Fused: each block stages hi/lo chunks into LDS directly from emb (4
// coalesced float4 loads -> register bf16 split -> swizzled ds_write_b128;
// loads for chunk c+1 issued BEFORE chunk c's compute so L2 latency hides
// under MFMAs). e2 computed in-block, exact sequential chain. Same swizzled
// granule map as R13 (write side also conflict-free: 8 lanes/bank-quartet).

constexpr int K      = 512;
constexpr int D      = 64;
constexpr int NPTS   = 16 * 4096;    // 65536
constexpr int BLOCK  = 256;
constexpr int PPB    = 64;           // points per block (4 waves x 16)
constexpr int CHUNK  = 64;           // codes per LDS chunk
constexpr int NCHUNK = K / CHUNK;    // 8
constexpr int GPC    = CHUNK * 8;    // 512 16B-granules per chunk per array

typedef __attribute__((ext_vector_type(8))) short  short8;
typedef __attribute__((ext_vector_type(4))) float  f32x4;

__device__ inline unsigned short bf16_rne(float f) {
    unsigned u = __builtin_bit_cast(unsigned, f);
    u += 0x7fffu + ((u >> 16) & 1u);
    return (unsigned short)(u >> 16);
}
__device__ inline float bf16_f32(unsigned short h) {
    unsigned u = (unsigned)h << 16;
    return __builtin_bit_cast(float, u);
}

__global__ __launch_bounds__(BLOCK, 4)
void vq_fused(const float* __restrict__ z,
              const float* __restrict__ emb,
              float* __restrict__ out)
{
    __shared__ short8 Ahi[2][GPC];    // 2 x 8 KiB
    __shared__ short8 Alo[2][GPC];    // 2 x 8 KiB
    __shared__ float4 e2L4[K / 4];    // 2 KiB
    __shared__ int    bidx_s[PPB];

    const int tid = threadIdx.x;
    const int w   = tid >> 6;         // wave -> owns point-tile w
    const int l   = tid & 63;
    const int col = l & 15;           // point within tile
    const int kg  = l >> 4;           // k-group / code-row group

    const float4* zf4 = reinterpret_cast<const float4*>(z);
    const float4* ef4 = reinterpret_cast<const float4*>(emb);
    float4*       of4 = reinterpret_cast<float4*>(out);

    const int base = blockIdx.x * PPB;
    const int pt   = base + w * 16 + col;   // this lane's point

    // ---- staging helpers: thread owns 16 consecutive floats of a chunk ----
    // chunk row = c*64 + (tid>>2), elems [(tid&3)*16, +16) = granules s0,s0+1
    const int codeL = tid >> 2;
    const int s0    = (tid & 3) * 2;
    const int g0    = codeL * 8 + ( s0      ^ (codeL & 7));
    const int g1    = codeL * 8 + ((s0 + 1) ^ (codeL & 7));

    auto loadChunk = [&](int c, float4* st) {
        const float4* p = ef4 + (c * CHUNK + codeL) * 16 + (tid & 3) * 4;
        st[0] = p[0]; st[1] = p[1]; st[2] = p[2]; st[3] = p[3];
    };
    auto writeChunk = [&](int b, const float4* st) {
        float xs[16];
        xs[ 0]=st[0].x; xs[ 1]=st[0].y; xs[ 2]=st[0].z; xs[ 3]=st[0].w;
        xs[ 4]=st[1].x; xs[ 5]=st[1].y; xs[ 6]=st[1].z; xs[ 7]=st[1].w;
        xs[ 8]=st[2].x; xs[ 9]=st[2].y; xs[10]=st[2].z; xs[11]=st[2].w;
        xs[12]=st[3].x; xs[13]=st[3].y; xs[14]=st[3].z; xs[15]=st[3].w;
        short8 h0, h1, l0, l1;
        #pragma unroll
        for (int e = 0; e < 8; ++e) {
            const unsigned short ha = bf16_rne(xs[e]);
            const float ra = xs[e] - bf16_f32(ha);        // exact (Sterbenz)
            h0[e] = (short)ha;  l0[e] = (short)bf16_rne(ra);
            const unsigned short hb = bf16_rne(xs[8 + e]);
            const float rb = xs[8 + e] - bf16_f32(hb);    // exact
            h1[e] = (short)hb;  l1[e] = (short)bf16_rne(rb);
        }
        Ahi[b][g0] = h0;  Ahi[b][g1] = h1;
        Alo[b][g0] = l0;  Alo[b][g1] = l1;
    };

    // ---- issue chunk-0 loads first (L2 latency hides under e2/x2 work) ----
    float4 stA[4], stB[4];
    loadChunk(0, stA);

    // ---- e2 in-block: 2 codes/thread, exact sequential unfused chain ----
    #pragma unroll
    for (int cc = 0; cc < 2; ++cc) {
        const int k = cc * BLOCK + tid;
        const float4* row = ef4 + k * 16;
        float s = 0.0f;
        {
            #pragma clang fp contract(off)
            #pragma unroll
            for (int i = 0; i < 16; ++i) {
                float4 q = row[i];
                s = s + q.x * q.x;
                s = s + q.y * q.y;
                s = s + q.z * q.z;
                s = s + q.w * q.w;
            }
        }
        reinterpret_cast<float*>(e2L4)[k] = s;
    }

    // ---- x2 for this lane's point, exact sequential unfused chain ----
    float x2v = 0.0f;
    {
        #pragma clang fp contract(off)
        #pragma unroll
        for (int i = 0; i < 16; ++i) {
            float4 q = zf4[pt * 16 + i];
            x2v = x2v + q.x * q.x;
            x2v = x2v + q.y * q.y;
            x2v = x2v + q.z * q.z;
            x2v = x2v + q.w * q.w;
        }
    }

    // ---- B-frags for this wave's point-tile (identical build to R13) ----
    short8 bh[2], bl[2];
    #pragma unroll
    for (int kt = 0; kt < 2; ++kt) {
        const float4 va = zf4[pt * 16 + kt * 8 + kg * 2];
        const float4 vb = zf4[pt * 16 + kt * 8 + kg * 2 + 1];
        const float xs[8] = {va.x, va.y, va.z, va.w, vb.x, vb.y, vb.z, vb.w};
        #pragma unroll
        for (int e = 0; e < 8; ++e) {
            const unsigned short h = bf16_rne(xs[e]);
            const float r = xs[e] - bf16_f32(h);   // exact
            bh[kt][e] = (short)h;
            bl[kt][e] = (short)bf16_rne(r);
        }
    }

    writeChunk(0, stA);
    __syncthreads();   // chunk 0 + e2L resident

    // Independent argmin slot per tile-position (R13, proven semantics).
    float bv0 = INFINITY, bv1 = INFINITY, bv2 = INFINITY, bv3 = INFINITY;
    int   ix0 = 0, ix1 = 0, ix2 = 0, ix3 = 0;

    auto computeTiles = [&](int c, int b) {
        #pragma unroll
        for (int t = 0; t < 4; ++t) {
            const int slot0 = ((t * 16 + col) << 3) | (kg ^ (col & 7)); // kt=0
            const short8 ah0 = Ahi[b][slot0];
            const short8 ah1 = Ahi[b][slot0 ^ 4];                        // kt=1
            const short8 al0 = Alo[b][slot0];
            const short8 al1 = Alo[b][slot0 ^ 4];

            f32x4 acc = {0.f, 0.f, 0.f, 0.f};
            // same term order as R5/R7/R8/R12/R13: per kt {al*bh, ah*bl, ah*bh}
            acc = __builtin_amdgcn_mfma_f32_16x16x32_bf16(al0, bh[0], acc, 0, 0, 0);
            acc = __builtin_amdgcn_mfma_f32_16x16x32_bf16(ah0, bl[0], acc, 0, 0, 0);
            acc = __builtin_amdgcn_mfma_f32_16x16x32_bf16(ah0, bh[0], acc, 0, 0, 0);
            acc = __builtin_amdgcn_mfma_f32_16x16x32_bf16(al1, bh[1], acc, 0, 0, 0);
            acc = __builtin_amdgcn_mfma_f32_16x16x32_bf16(ah1, bl[1], acc, 0, 0, 0);
            acc = __builtin_amdgcn_mfma_f32_16x16x32_bf16(ah1, bh[1], acc, 0, 0, 0);

            const int   kbase = c * CHUNK + t * 16 + kg * 4;
            const float4 e2v  = e2L4[kbase >> 2];   // broadcast ds_read
            const float d0 = (x2v - 2.0f * acc[0]) + e2v.x;
            const float d1 = (x2v - 2.0f * acc[1]) + e2v.y;
            const float d2 = (x2v - 2.0f * acc[2]) + e2v.z;
            const float d3 = (x2v - 2.0f * acc[3]) + e2v.w;

            float mv01 = d0; int mi01 = kbase + 0;
            if (d1 < mv01) { mv01 = d1; mi01 = kbase + 1; }
            float mv23 = d2; int mi23 = kbase + 2;
            if (d3 < mv23) { mv23 = d3; mi23 = kbase + 3; }
            float mv = mv01; int mi = mi01;
            if (mv23 < mv) { mv = mv23; mi = mi23; }
            if (t == 0) { if (mv < bv0) { bv0 = mv; ix0 = mi; } }
            if (t == 1) { if (mv < bv1) { bv1 = mv; ix1 = mi; } }
            if (t == 2) { if (mv < bv2) { bv2 = mv; ix2 = mi; } }
            if (t == 3) { if (mv < bv3) { bv3 = mv; ix3 = mi; } }
        }
    };

    // k-loop: unrolled pairs with named ping-pong staging regs (rule #20)
    #pragma unroll
    for (int h = 0; h < NCHUNK / 2; ++h) {
        const int c0 = 2 * h, c1 = 2 * h + 1;
        if (c0 + 1 < NCHUNK) loadChunk(c0 + 1, stB);   // issue early
        computeTiles(c0, 0);
        if (c0 + 1 < NCHUNK) writeChunk(1, stB);       // lands after compute
        __syncthreads();
        if (c1 + 1 < NCHUNK) loadChunk(c1 + 1, stA);
        computeTiles(c1, 1);
        if (c1 + 1 < NCHUNK) writeChunk(0, stA);
        __syncthreads();
    }

    // merge the 4 slots: lexicographic (val, idx) == global first-index
    float best = bv0; int bi = ix0;
    if (bv1 < best || (bv1 == best && ix1 < bi)) { best = bv1; bi = ix1; }
    if (bv2 < best || (bv2 == best && ix2 < bi)) { best = bv2; bi = ix2; }
    if (bv3 < best || (bv3 == best && ix3 < bi)) { best = bv3; bi = ix3; }

    // combine 4 kg-groups (lanes sharing a column): lexicographic (dist, idx)
    #pragma unroll
    for (int off = 16; off < 64; off <<= 1) {
        const float ov = __shfl_xor(best, off);
        const int   oi = __shfl_xor(bi,   off);
        if (ov < best || (ov == best && oi < bi)) { best = ov; bi = oi; }
    }
    if (l < 16) bidx_s[w * 16 + col] = bi;
    __syncthreads();

    // dense epilogue: lane-linear float4 stores, straight-through (q+x)-x
    #pragma unroll
    for (int i = 0; i < (PPB * 16) / BLOCK; ++i) {   // 4 iters
        const int idx = i * BLOCK + tid;
        const int p   = idx >> 4;
        const int j   = idx & 15;
        const float4 q = ef4[bidx_s[p] * 16 + j];
        const float4 x = zf4[(base + p) * 16 + j];
        float4 o;
        o.x = (q.x + x.x) - x.x;
        o.y = (q.y + x.y) - x.y;
        o.z = (q.z + x.z) - x.z;
        o.w = (q.w + x.w) - x.w;
        of4[(base + p) * 16 + j] = o;
    }
}

extern "C" void kernel_launch(void* const* d_in, const int* in_sizes, int n_in,
                              void* d_out, int out_size, void* d_ws, size_t ws_size,
                              hipStream_t stream) {
    const float* z   = (const float*)d_in[0];
    const float* emb = (const float*)d_in[1];
    float* out = (float*)d_out;
    (void)d_ws; (void)ws_size;

    vq_fused<<<NPTS / PPB, BLOCK, 0, stream>>>(z, emb, out);
}

// Round 16
// 52.809 us; speedup vs baseline: 1.1348x; 1.1348x over previous
//
#include <hip/hip_runtime.h>
#include <math.h>

// st_VQEmbedding via LDS-staged MFMA GEMM (R13 skeleton + FORCED 4-chain ILP).
// z [65536,64] f32, emb [512,64] f32 -> out = emb[argmin_k (x2-2dot)+e2],
// straight-through (q+x)-x. dot via bf16 2-term split MFMA (al*bh + ah*bl +
// ah*bh, fp32 accum) -- bit-identical chains/term order/tie-break to
// R5/R7/R8/R12/R13 (all passed absmax 0.0).
//
// R16: R13's "independent slots" were re-serialized by the compiler (VGPR=52
// can't hold 4 live acc chains -> it reused one acc set per tile, making
// R13 == R12; identical 36.9us). Force the interleave: per chunk, hoist all
// 16 A-frag ds_reads + 4 e2 reads, then emit the 24 MFMAs as six round-robin
// QUADS (term m of tiles 0..3) separated by sched_barrier(0) -- the compiler
// cannot complete one chain before starting the next, so 4 chains stay live
// and the matrix pipe runs at issue throughput, not dependent latency.
// Per-acc term order unchanged -> dist bits identical.

constexpr int K      = 512;
constexpr int D      = 64;
constexpr int NPTS   = 16 * 4096;    // 65536
constexpr int BLOCK  = 256;
constexpr int PPB    = 64;           // points per block (4 waves x 16)
constexpr int CHUNK  = 64;           // codes per LDS chunk
constexpr int NCHUNK = K / CHUNK;    // 8
constexpr int GPC    = CHUNK * 8;    // 512 16B-granules per chunk per array

typedef __attribute__((ext_vector_type(8))) short  short8;
typedef __attribute__((ext_vector_type(4))) float  f32x4;

#define AS_G (const __attribute__((address_space(1))) void*)
#define AS_L (__attribute__((address_space(3))) void*)

__device__ inline unsigned short bf16_rne(float f) {
    unsigned u = __builtin_bit_cast(unsigned, f);
    u += 0x7fffu + ((u >> 16) & 1u);
    return (unsigned short)(u >> 16);
}
__device__ inline float bf16_f32(unsigned short h) {
    unsigned u = (unsigned)h << 16;
    return __builtin_bit_cast(float, u);
}

// ---- prep: e2 (exact chain) + bf16 hi/lo split, written pre-swizzled ------
// thread t: code k = t>>3, d-slot s = t&7 (d = s*8..s*8+7).
// ws granule index = (k>>6)*GPC + (k&63)*8 + (s ^ (k&7))   [identical to R13]
__global__ void prep_emb(const float* __restrict__ emb,
                         float* __restrict__ e2,
                         short8* __restrict__ wsHi,
                         short8* __restrict__ wsLo)
{
    const int gid = blockIdx.x * 256 + threadIdx.x;   // 0..4095
    const int k = gid >> 3;
    const int s = gid & 7;

    const float4* row = reinterpret_cast<const float4*>(emb + k * D);
    float v[64];
    #pragma unroll
    for (int i = 0; i < 16; ++i) {
        float4 q = row[i];
        v[4*i+0] = q.x; v[4*i+1] = q.y; v[4*i+2] = q.z; v[4*i+3] = q.w;
    }
    if (s == 0) {   // exact sequential unfused e2 (same chain as R1-R13)
        float acc = 0.0f;
        {
            #pragma clang fp contract(off)
            #pragma unroll
            for (int d = 0; d < 64; ++d) acc = acc + v[d] * v[d];
        }
        e2[k] = acc;
    }
    short8 hi, lo;
    #pragma unroll
    for (int e = 0; e < 8; ++e) {
        const float f = v[s * 8 + e];
        const unsigned short h = bf16_rne(f);
        const float r = f - bf16_f32(h);          // exact (Sterbenz)
        hi[e] = (short)h;
        lo[e] = (short)bf16_rne(r);
    }
    const int slot = (k >> 6) * GPC + (k & 63) * 8 + (s ^ (k & 7));
    wsHi[slot] = hi;
    wsLo[slot] = lo;
}

// ---- main: LDS-staged MFMA argmin + gather ---------------------------------
__global__ __launch_bounds__(BLOCK, 4)
void vq_mfma(const float* __restrict__ z,
             const float* __restrict__ emb,
             const float* __restrict__ e2,
             const short8* __restrict__ wsHi,
             const short8* __restrict__ wsLo,
             float* __restrict__ out)
{
    __shared__ short8 Ahi[2][GPC];    // 2 x 8 KiB
    __shared__ short8 Alo[2][GPC];    // 2 x 8 KiB
    __shared__ float4 e2L[K / 4];     // 2 KiB
    __shared__ int    bidx_s[PPB];

    const int tid = threadIdx.x;
    const int w   = tid >> 6;         // wave -> owns point-tile w
    const int l   = tid & 63;
    const int col = l & 15;           // point within tile
    const int kg  = l >> 4;           // k-group / code-row group

    const float4* zf4 = reinterpret_cast<const float4*>(z);
    const float4* ef4 = reinterpret_cast<const float4*>(emb);
    float4*       of4 = reinterpret_cast<float4*>(out);

    const int base = blockIdx.x * PPB;
    const int pt   = base + w * 16 + col;   // this lane's point

    // stage chunk c (64 codes, hi+lo) into buffer b: pure linear copy,
    // source already in LDS-image (swizzled) order.
    auto stage = [&](int c, int b) {
        const short8* sH = wsHi + c * GPC;
        const short8* sL = wsLo + c * GPC;
        #pragma unroll
        for (int i = 0; i < 2; ++i) {
            const int f = i * 256 + tid;
            __builtin_amdgcn_global_load_lds(AS_G(sH + f),
                                             AS_L(&Ahi[b][f]), 16, 0, 0);
            __builtin_amdgcn_global_load_lds(AS_G(sL + f),
                                             AS_L(&Alo[b][f]), 16, 0, 0);
        }
    };

    stage(0, 0);   // in flight during x2 / B-frag build
    if (tid < K / 4)   // e2 -> LDS, lane-linear 16B granules
        __builtin_amdgcn_global_load_lds(AS_G(e2 + tid * 4),
                                         AS_L(&e2L[tid]), 16, 0, 0);

    // ---- x2 for this lane's point, exact sequential unfused chain ----
    float x2v = 0.0f;
    {
        #pragma clang fp contract(off)
        #pragma unroll
        for (int i = 0; i < 16; ++i) {
            float4 q = zf4[pt * 16 + i];
            x2v = x2v + q.x * q.x;
            x2v = x2v + q.y * q.y;
            x2v = x2v + q.z * q.z;
            x2v = x2v + q.w * q.w;
        }
    }

    // ---- B-frags for this wave's point-tile (identical build to R13) ----
    short8 bh[2], bl[2];
    #pragma unroll
    for (int kt = 0; kt < 2; ++kt) {
        const float4 va = zf4[pt * 16 + kt * 8 + kg * 2];
        const float4 vb = zf4[pt * 16 + kt * 8 + kg * 2 + 1];
        const float xs[8] = {va.x, va.y, va.z, va.w, vb.x, vb.y, vb.z, vb.w};
        #pragma unroll
        for (int e = 0; e < 8; ++e) {
            const unsigned short h = bf16_rne(xs[e]);
            const float r = xs[e] - bf16_f32(h);   // exact
            bh[kt][e] = (short)h;
            bl[kt][e] = (short)bf16_rne(r);
        }
    }

    __syncthreads();   // chunk 0 + e2L staged

    // Independent argmin slot per tile-position (R13 semantics).
    float bv0 = INFINITY, bv1 = INFINITY, bv2 = INFINITY, bv3 = INFINITY;
    int   ix0 = 0, ix1 = 0, ix2 = 0, ix3 = 0;
    int   b = 0;

    for (int c = 0; c < NCHUNK; ++c) {
        if (c + 1 < NCHUNK) stage(c + 1, b ^ 1);

        // ---- phase 1: hoist ALL A-frag + e2 reads for the 4 tiles ----
        short8 AH0[4], AH1[4], AL0[4], AL1[4];
        float4 E2[4];
        #pragma unroll
        for (int t = 0; t < 4; ++t) {
            const int slot0 = ((t * 16 + col) << 3) | (kg ^ (col & 7)); // kt=0
            AH0[t] = Ahi[b][slot0];
            AH1[t] = Ahi[b][slot0 ^ 4];                                  // kt=1
            AL0[t] = Alo[b][slot0];
            AL1[t] = Alo[b][slot0 ^ 4];
            E2[t]  = e2L[(c * CHUNK + t * 16 + kg * 4) >> 2];
        }

        f32x4 acc[4];
        #pragma unroll
        for (int t = 0; t < 4; ++t) acc[t] = (f32x4){0.f, 0.f, 0.f, 0.f};

        __builtin_amdgcn_sched_barrier(0);

        // ---- phase 2: 24 MFMAs as 6 round-robin quads; sched_barrier(0)
        // between quads keeps all 4 acc chains live (no re-serialization).
        // Per-acc term order unchanged: {al0*bh0, ah0*bl0, ah0*bh0,
        //                               al1*bh1, ah1*bl1, ah1*bh1}.
        #pragma unroll
        for (int t = 0; t < 4; ++t)
            acc[t] = __builtin_amdgcn_mfma_f32_16x16x32_bf16(AL0[t], bh[0], acc[t], 0, 0, 0);
        __builtin_amdgcn_sched_barrier(0);
        #pragma unroll
        for (int t = 0; t < 4; ++t)
            acc[t] = __builtin_amdgcn_mfma_f32_16x16x32_bf16(AH0[t], bl[0], acc[t], 0, 0, 0);
        __builtin_amdgcn_sched_barrier(0);
        #pragma unroll
        for (int t = 0; t < 4; ++t)
            acc[t] = __builtin_amdgcn_mfma_f32_16x16x32_bf16(AH0[t], bh[0], acc[t], 0, 0, 0);
        __builtin_amdgcn_sched_barrier(0);
        #pragma unroll
        for (int t = 0; t < 4; ++t)
            acc[t] = __builtin_amdgcn_mfma_f32_16x16x32_bf16(AL1[t], bh[1], acc[t], 0, 0, 0);
        __builtin_amdgcn_sched_barrier(0);
        #pragma unroll
        for (int t = 0; t < 4; ++t)
            acc[t] = __builtin_amdgcn_mfma_f32_16x16x32_bf16(AH1[t], bl[1], acc[t], 0, 0, 0);
        __builtin_amdgcn_sched_barrier(0);
        #pragma unroll
        for (int t = 0; t < 4; ++t)
            acc[t] = __builtin_amdgcn_mfma_f32_16x16x32_bf16(AH1[t], bh[1], acc[t], 0, 0, 0);
        __builtin_amdgcn_sched_barrier(0);

        // ---- phase 3: dists + per-slot argmin (bit-identical chain) ----
        #pragma unroll
        for (int t = 0; t < 4; ++t) {
            const int   kbase = c * CHUNK + t * 16 + kg * 4;
            const float d0 = (x2v - 2.0f * acc[t][0]) + E2[t].x;
            const float d1 = (x2v - 2.0f * acc[t][1]) + E2[t].y;
            const float d2 = (x2v - 2.0f * acc[t][2]) + E2[t].z;
            const float d3 = (x2v - 2.0f * acc[t][3]) + E2[t].w;

            float mv01 = d0; int mi01 = kbase + 0;
            if (d1 < mv01) { mv01 = d1; mi01 = kbase + 1; }
            float mv23 = d2; int mi23 = kbase + 2;
            if (d3 < mv23) { mv23 = d3; mi23 = kbase + 3; }
            float mv = mv01; int mi = mi01;
            if (mv23 < mv) { mv = mv23; mi = mi23; }
            if (t == 0) { if (mv < bv0) { bv0 = mv; ix0 = mi; } }
            if (t == 1) { if (mv < bv1) { bv1 = mv; ix1 = mi; } }
            if (t == 2) { if (mv < bv2) { bv2 = mv; ix2 = mi; } }
            if (t == 3) { if (mv < bv3) { bv3 = mv; ix3 = mi; } }
        }
        __syncthreads();   // drains stage vmcnt + all waves done with buf b
        b ^= 1;
    }

    // merge the 4 slots: lexicographic (val, idx) == global first-index
    float best = bv0; int bi = ix0;
    if (bv1 < best || (bv1 == best && ix1 < bi)) { best = bv1; bi = ix1; }
    if (bv2 < best || (bv2 == best && ix2 < bi)) { best = bv2; bi = ix2; }
    if (bv3 < best || (bv3 == best && ix3 < bi)) { best = bv3; bi = ix3; }

    // combine 4 kg-groups (lanes sharing a column): lexicographic (dist, idx)
    #pragma unroll
    for (int off = 16; off < 64; off <<= 1) {
        const float ov = __shfl_xor(best, off);
        const int   oi = __shfl_xor(bi,   off);
        if (ov < best || (ov == best && oi < bi)) { best = ov; bi = oi; }
    }
    if (l < 16) bidx_s[w * 16 + col] = bi;
    __syncthreads();

    // dense epilogue: lane-linear float4 stores, straight-through (q+x)-x
    #pragma unroll
    for (int i = 0; i < (PPB * 16) / BLOCK; ++i) {   // 4 iters
        const int idx = i * BLOCK + tid;
        const int p   = idx >> 4;
        const int j   = idx & 15;
        const float4 q = ef4[bidx_s[p] * 16 + j];
        const float4 x = zf4[(base + p) * 16 + j];
        float4 o;
        o.x = (q.x + x.x) - x.x;
        o.y = (q.y + x.y) - x.y;
        o.z = (q.z + x.z) - x.z;
        o.w = (q.w + x.w) - x.w;
        of4[(base + p) * 16 + j] = o;
    }
}

extern "C" void kernel_launch(void* const* d_in, const int* in_sizes, int n_in,
                              void* d_out, int out_size, void* d_ws, size_t ws_size,
                              hipStream_t stream) {
    const float* z   = (const float*)d_in[0];
    const float* emb = (const float*)d_in[1];
    float* out = (float*)d_out;

    // ws: e2 f32[512] (2KB) | wsHi short8[4096] (64KB) | wsLo short8[4096] (64KB)
    float*  e2   = (float*)d_ws;
    short8* wsHi = (short8*)((char*)d_ws + 2048);
    short8* wsLo = (short8*)((char*)d_ws + 2048 + 65536);

    prep_emb<<<16, 256, 0, stream>>>(emb, e2, wsHi, wsLo);
    vq_mfma<<<NPTS / PPB, BLOCK, 0, stream>>>(z, emb, e2, wsHi, wsLo, out);
}

// Round 17
// 37.237 us; speedup vs baseline: 1.6094x; 1.4182x over previous
//
#include <hip/hip_runtime.h>
#include <math.h>

// st_VQEmbedding via LDS-staged MFMA GEMM (R16 structure + pinned occupancy).
// z [65536,64] f32, emb [512,64] f32 -> out = emb[argmin_k (x2-2dot)+e2],
// straight-through (q+x)-x. dot via bf16 2-term split MFMA (al*bh + ah*bl +
// ah*bh, fp32 accum) -- bit-identical chains/term order/tie-break to
// R5/R7/R8/R12/R13 (all passed absmax 0.0).
//
// R17: the R-series pathology is the compiler targeting 8 waves/SIMD
// (VGPR<=64) and spilling/re-serializing to get there (R3:44, R11:84+spill,
// R13:52 re-serialized, R16:64 + 97MB scratch WRITE). HW occupancy is
// LDS-capped at 4 blocks/CU regardless. amdgpu_waves_per_eu(4,4) pins the
// compiler's occupancy target to 4 waves/EU -> 128-VGPR budget, so the
// forced 4-chain MFMA interleave (round-robin quads + sched_barrier) can
// actually keep its operands in registers. E2 un-hoisted (read post-MFMA)
// to stay under 128.

constexpr int K      = 512;
constexpr int D      = 64;
constexpr int NPTS   = 16 * 4096;    // 65536
constexpr int BLOCK  = 256;
constexpr int PPB    = 64;           // points per block (4 waves x 16)
constexpr int CHUNK  = 64;           // codes per LDS chunk
constexpr int NCHUNK = K / CHUNK;    // 8
constexpr int GPC    = CHUNK * 8;    // 512 16B-granules per chunk per array

typedef __attribute__((ext_vector_type(8))) short  short8;
typedef __attribute__((ext_vector_type(4))) float  f32x4;

#define AS_G (const __attribute__((address_space(1))) void*)
#define AS_L (__attribute__((address_space(3))) void*)

__device__ inline unsigned short bf16_rne(float f) {
    unsigned u = __builtin_bit_cast(unsigned, f);
    u += 0x7fffu + ((u >> 16) & 1u);
    return (unsigned short)(u >> 16);
}
__device__ inline float bf16_f32(unsigned short h) {
    unsigned u = (unsigned)h << 16;
    return __builtin_bit_cast(float, u);
}

// ---- prep: e2 (exact chain) + bf16 hi/lo split, written pre-swizzled ------
// thread t: code k = t>>3, d-slot s = t&7 (d = s*8..s*8+7).
// ws granule index = (k>>6)*GPC + (k&63)*8 + (s ^ (k&7))   [identical to R13]
__global__ void prep_emb(const float* __restrict__ emb,
                         float* __restrict__ e2,
                         short8* __restrict__ wsHi,
                         short8* __restrict__ wsLo)
{
    const int gid = blockIdx.x * 256 + threadIdx.x;   // 0..4095
    const int k = gid >> 3;
    const int s = gid & 7;

    const float4* row = reinterpret_cast<const float4*>(emb + k * D);
    float v[64];
    #pragma unroll
    for (int i = 0; i < 16; ++i) {
        float4 q = row[i];
        v[4*i+0] = q.x; v[4*i+1] = q.y; v[4*i+2] = q.z; v[4*i+3] = q.w;
    }
    if (s == 0) {   // exact sequential unfused e2 (same chain as R1-R13)
        float acc = 0.0f;
        {
            #pragma clang fp contract(off)
            #pragma unroll
            for (int d = 0; d < 64; ++d) acc = acc + v[d] * v[d];
        }
        e2[k] = acc;
    }
    short8 hi, lo;
    #pragma unroll
    for (int e = 0; e < 8; ++e) {
        const float f = v[s * 8 + e];
        const unsigned short h = bf16_rne(f);
        const float r = f - bf16_f32(h);          // exact (Sterbenz)
        hi[e] = (short)h;
        lo[e] = (short)bf16_rne(r);
    }
    const int slot = (k >> 6) * GPC + (k & 63) * 8 + (s ^ (k & 7));
    wsHi[slot] = hi;
    wsLo[slot] = lo;
}

// ---- main: LDS-staged MFMA argmin + gather ---------------------------------
__global__ __launch_bounds__(BLOCK)
__attribute__((amdgpu_waves_per_eu(4, 4)))
void vq_mfma(const float* __restrict__ z,
             const float* __restrict__ emb,
             const float* __restrict__ e2,
             const short8* __restrict__ wsHi,
             const short8* __restrict__ wsLo,
             float* __restrict__ out)
{
    __shared__ short8 Ahi[2][GPC];    // 2 x 8 KiB
    __shared__ short8 Alo[2][GPC];    // 2 x 8 KiB
    __shared__ float4 e2L[K / 4];     // 2 KiB
    __shared__ int    bidx_s[PPB];

    const int tid = threadIdx.x;
    const int w   = tid >> 6;         // wave -> owns point-tile w
    const int l   = tid & 63;
    const int col = l & 15;           // point within tile
    const int kg  = l >> 4;           // k-group / code-row group

    const float4* zf4 = reinterpret_cast<const float4*>(z);
    const float4* ef4 = reinterpret_cast<const float4*>(emb);
    float4*       of4 = reinterpret_cast<float4*>(out);

    const int base = blockIdx.x * PPB;
    const int pt   = base + w * 16 + col;   // this lane's point

    // stage chunk c (64 codes, hi+lo) into buffer b: pure linear copy,
    // source already in LDS-image (swizzled) order.
    auto stage = [&](int c, int b) {
        const short8* sH = wsHi + c * GPC;
        const short8* sL = wsLo + c * GPC;
        #pragma unroll
        for (int i = 0; i < 2; ++i) {
            const int f = i * 256 + tid;
            __builtin_amdgcn_global_load_lds(AS_G(sH + f),
                                             AS_L(&Ahi[b][f]), 16, 0, 0);
            __builtin_amdgcn_global_load_lds(AS_G(sL + f),
                                             AS_L(&Alo[b][f]), 16, 0, 0);
        }
    };

    stage(0, 0);   // in flight during x2 / B-frag build
    if (tid < K / 4)   // e2 -> LDS, lane-linear 16B granules
        __builtin_amdgcn_global_load_lds(AS_G(e2 + tid * 4),
                                         AS_L(&e2L[tid]), 16, 0, 0);

    // ---- x2 for this lane's point, exact sequential unfused chain ----
    float x2v = 0.0f;
    {
        #pragma clang fp contract(off)
        #pragma unroll
        for (int i = 0; i < 16; ++i) {
            float4 q = zf4[pt * 16 + i];
            x2v = x2v + q.x * q.x;
            x2v = x2v + q.y * q.y;
            x2v = x2v + q.z * q.z;
            x2v = x2v + q.w * q.w;
        }
    }

    // ---- B-frags for this wave's point-tile (identical build to R13) ----
    short8 bh[2], bl[2];
    #pragma unroll
    for (int kt = 0; kt < 2; ++kt) {
        const float4 va = zf4[pt * 16 + kt * 8 + kg * 2];
        const float4 vb = zf4[pt * 16 + kt * 8 + kg * 2 + 1];
        const float xs[8] = {va.x, va.y, va.z, va.w, vb.x, vb.y, vb.z, vb.w};
        #pragma unroll
        for (int e = 0; e < 8; ++e) {
            const unsigned short h = bf16_rne(xs[e]);
            const float r = xs[e] - bf16_f32(h);   // exact
            bh[kt][e] = (short)h;
            bl[kt][e] = (short)bf16_rne(r);
        }
    }

    __syncthreads();   // chunk 0 + e2L staged

    // Independent argmin slot per tile-position (R13 semantics).
    float bv0 = INFINITY, bv1 = INFINITY, bv2 = INFINITY, bv3 = INFINITY;
    int   ix0 = 0, ix1 = 0, ix2 = 0, ix3 = 0;
    int   b = 0;

    for (int c = 0; c < NCHUNK; ++c) {
        if (c + 1 < NCHUNK) stage(c + 1, b ^ 1);

        // ---- phase 1: hoist ALL A-frag reads for the 4 tiles (64 VGPR) ----
        short8 AH0[4], AH1[4], AL0[4], AL1[4];
        #pragma unroll
        for (int t = 0; t < 4; ++t) {
            const int slot0 = ((t * 16 + col) << 3) | (kg ^ (col & 7)); // kt=0
            AH0[t] = Ahi[b][slot0];
            AH1[t] = Ahi[b][slot0 ^ 4];                                  // kt=1
            AL0[t] = Alo[b][slot0];
            AL1[t] = Alo[b][slot0 ^ 4];
        }

        f32x4 acc[4];
        #pragma unroll
        for (int t = 0; t < 4; ++t) acc[t] = (f32x4){0.f, 0.f, 0.f, 0.f};

        __builtin_amdgcn_sched_barrier(0);

        // ---- phase 2: 24 MFMAs as 6 round-robin quads; sched_barrier(0)
        // between quads keeps all 4 acc chains live. Per-acc term order
        // unchanged: {al0*bh0, ah0*bl0, ah0*bh0, al1*bh1, ah1*bl1, ah1*bh1}.
        #pragma unroll
        for (int t = 0; t < 4; ++t)
            acc[t] = __builtin_amdgcn_mfma_f32_16x16x32_bf16(AL0[t], bh[0], acc[t], 0, 0, 0);
        __builtin_amdgcn_sched_barrier(0);
        #pragma unroll
        for (int t = 0; t < 4; ++t)
            acc[t] = __builtin_amdgcn_mfma_f32_16x16x32_bf16(AH0[t], bl[0], acc[t], 0, 0, 0);
        __builtin_amdgcn_sched_barrier(0);
        #pragma unroll
        for (int t = 0; t < 4; ++t)
            acc[t] = __builtin_amdgcn_mfma_f32_16x16x32_bf16(AH0[t], bh[0], acc[t], 0, 0, 0);
        __builtin_amdgcn_sched_barrier(0);
        #pragma unroll
        for (int t = 0; t < 4; ++t)
            acc[t] = __builtin_amdgcn_mfma_f32_16x16x32_bf16(AL1[t], bh[1], acc[t], 0, 0, 0);
        __builtin_amdgcn_sched_barrier(0);
        #pragma unroll
        for (int t = 0; t < 4; ++t)
            acc[t] = __builtin_amdgcn_mfma_f32_16x16x32_bf16(AH1[t], bl[1], acc[t], 0, 0, 0);
        __builtin_amdgcn_sched_barrier(0);
        #pragma unroll
        for (int t = 0; t < 4; ++t)
            acc[t] = __builtin_amdgcn_mfma_f32_16x16x32_bf16(AH1[t], bh[1], acc[t], 0, 0, 0);
        __builtin_amdgcn_sched_barrier(0);

        // ---- phase 3: dists + per-slot argmin (bit-identical chain);
        // e2 read here (post-MFMA) to keep VGPR under the 128 budget.
        #pragma unroll
        for (int t = 0; t < 4; ++t) {
            const int   kbase = c * CHUNK + t * 16 + kg * 4;
            const float4 e2v  = e2L[kbase >> 2];   // broadcast ds_read
            const float d0 = (x2v - 2.0f * acc[t][0]) + e2v.x;
            const float d1 = (x2v - 2.0f * acc[t][1]) + e2v.y;
            const float d2 = (x2v - 2.0f * acc[t][2]) + e2v.z;
            const float d3 = (x2v - 2.0f * acc[t][3]) + e2v.w;

            float mv01 = d0; int mi01 = kbase + 0;
            if (d1 < mv01) { mv01 = d1; mi01 = kbase + 1; }
            float mv23 = d2; int mi23 = kbase + 2;
            if (d3 < mv23) { mv23 = d3; mi23 = kbase + 3; }
            float mv = mv01; int mi = mi01;
            if (mv23 < mv) { mv = mv23; mi = mi23; }
            if (t == 0) { if (mv < bv0) { bv0 = mv; ix0 = mi; } }
            if (t == 1) { if (mv < bv1) { bv1 = mv; ix1 = mi; } }
            if (t == 2) { if (mv < bv2) { bv2 = mv; ix2 = mi; } }
            if (t == 3) { if (mv < bv3) { bv3 = mv; ix3 = mi; } }
        }
        __syncthreads();   // drains stage vmcnt + all waves done with buf b
        b ^= 1;
    }

    // merge the 4 slots: lexicographic (val, idx) == global first-index
    float best = bv0; int bi = ix0;
    if (bv1 < best || (bv1 == best && ix1 < bi)) { best = bv1; bi = ix1; }
    if (bv2 < best || (bv2 == best && ix2 < bi)) { best = bv2; bi = ix2; }
    if (bv3 < best || (bv3 == best && ix3 < bi)) { best = bv3; bi = ix3; }

    // combine 4 kg-groups (lanes sharing a column): lexicographic (dist, idx)
    #pragma unroll
    for (int off = 16; off < 64; off <<= 1) {
        const float ov = __shfl_xor(best, off);
        const int   oi = __shfl_xor(bi,   off);
        if (ov < best || (ov == best && oi < bi)) { best = ov; bi = oi; }
    }
    if (l < 16) bidx_s[w * 16 + col] = bi;
    __syncthreads();

    // dense epilogue: lane-linear float4 stores, straight-through (q+x)-x
    #pragma unroll
    for (int i = 0; i < (PPB * 16) / BLOCK; ++i) {   // 4 iters
        const int idx = i * BLOCK + tid;
        const int p   = idx >> 4;
        const int j   = idx & 15;
        const float4 q = ef4[bidx_s[p] * 16 + j];
        const float4 x = zf4[(base + p) * 16 + j];
        float4 o;
        o.x = (q.x + x.x) - x.x;
        o.y = (q.y + x.y) - x.y;
        o.z = (q.z + x.z) - x.z;
        o.w = (q.w + x.w) - x.w;
        of4[(base + p) * 16 + j] = o;
    }
}

extern "C" void kernel_launch(void* const* d_in, const int* in_sizes, int n_in,
                              void* d_out, int out_size, void* d_ws, size_t ws_size,
                              hipStream_t stream) {
    const float* z   = (const float*)d_in[0];
    const float* emb = (const float*)d_in[1];
    float* out = (float*)d_out;

    // ws: e2 f32[512] (2KB) | wsHi short8[4096] (64KB) | wsLo short8[4096] (64KB)
    float*  e2   = (float*)d_ws;
    short8* wsHi = (short8*)((char*)d_ws + 2048);
    short8* wsLo = (short8*)((char*)d_ws + 2048 + 65536);

    prep_emb<<<16, 256, 0, stream>>>(emb, e2, wsHi, wsLo);
    vq_mfma<<<NPTS / PPB, BLOCK, 0, stream>>>(z, emb, e2, wsHi, wsLo, out);
}

// Round 18
// 32.545 us; speedup vs baseline: 1.8414x; 1.1442x over previous
//
#include <hip/hip_runtime.h>
#include <math.h>

// st_VQEmbedding via LDS-staged MFMA GEMM (R13 base + coalesced z-tile LDS).
// z [65536,64] f32, emb [512,64] f32 -> out = emb[argmin_k (x2-2dot)+e2],
// straight-through (q+x)-x. dot via bf16 2-term split MFMA (al*bh + ah*bl +
// ah*bh, fp32 accum) -- bit-identical chains/term order/tie-break to
// R5/R7/R8/R12/R13 (all passed absmax 0.0).
//
// R18: last untested structural cost = scattered z-row loads (each wave64
// x2/B-frag load touches 64 cache lines at 256B stride; ~16k L1-line
// transactions/CU through the TA). Fix: stage the block's z-tile into LDS
// with COALESCED global loads (4 per thread), padded row stride 272B
// (16B-aligned; banks 2-way = free per m136), then source x2, B-frags and
// the epilogue x from LDS (kg duplicates = broadcast, free). Values and
// chain order identical -> absmax 0.0.

constexpr int K      = 512;
constexpr int D      = 64;
constexpr int NPTS   = 16 * 4096;    // 65536
constexpr int BLOCK  = 256;
constexpr int PPB    = 64;           // points per block (4 waves x 16)
constexpr int CHUNK  = 64;           // codes per LDS chunk
constexpr int NCHUNK = K / CHUNK;    // 8
constexpr int GPC    = CHUNK * 8;    // 512 16B-granules per chunk per array
constexpr int ZSTR   = 17;           // z-tile row stride in float4 (272 B)

typedef __attribute__((ext_vector_type(8))) short  short8;
typedef __attribute__((ext_vector_type(4))) float  f32x4;

#define AS_G (const __attribute__((address_space(1))) void*)
#define AS_L (__attribute__((address_space(3))) void*)

__device__ inline unsigned short bf16_rne(float f) {
    unsigned u = __builtin_bit_cast(unsigned, f);
    u += 0x7fffu + ((u >> 16) & 1u);
    return (unsigned short)(u >> 16);
}
__device__ inline float bf16_f32(unsigned short h) {
    unsigned u = (unsigned)h << 16;
    return __builtin_bit_cast(float, u);
}

// ---- prep: e2 (exact chain) + bf16 hi/lo split, written pre-swizzled ------
// thread t: code k = t>>3, d-slot s = t&7 (d = s*8..s*8+7).
// ws granule index = (k>>6)*GPC + (k&63)*8 + (s ^ (k&7))   [identical to R13]
__global__ void prep_emb(const float* __restrict__ emb,
                         float* __restrict__ e2,
                         short8* __restrict__ wsHi,
                         short8* __restrict__ wsLo)
{
    const int gid = blockIdx.x * 256 + threadIdx.x;   // 0..4095
    const int k = gid >> 3;
    const int s = gid & 7;

    const float4* row = reinterpret_cast<const float4*>(emb + k * D);
    float v[64];
    #pragma unroll
    for (int i = 0; i < 16; ++i) {
        float4 q = row[i];
        v[4*i+0] = q.x; v[4*i+1] = q.y; v[4*i+2] = q.z; v[4*i+3] = q.w;
    }
    if (s == 0) {   // exact sequential unfused e2 (same chain as R1-R17)
        float acc = 0.0f;
        {
            #pragma clang fp contract(off)
            #pragma unroll
            for (int d = 0; d < 64; ++d) acc = acc + v[d] * v[d];
        }
        e2[k] = acc;
    }
    short8 hi, lo;
    #pragma unroll
    for (int e = 0; e < 8; ++e) {
        const float f = v[s * 8 + e];
        const unsigned short h = bf16_rne(f);
        const float r = f - bf16_f32(h);          // exact (Sterbenz)
        hi[e] = (short)h;
        lo[e] = (short)bf16_rne(r);
    }
    const int slot = (k >> 6) * GPC + (k & 63) * 8 + (s ^ (k & 7));
    wsHi[slot] = hi;
    wsLo[slot] = lo;
}

// ---- main: LDS-staged MFMA argmin + gather ---------------------------------
__global__ __launch_bounds__(BLOCK, 3)
void vq_mfma(const float* __restrict__ z,
             const float* __restrict__ emb,
             const float* __restrict__ e2,
             const short8* __restrict__ wsHi,
             const short8* __restrict__ wsLo,
             float* __restrict__ out)
{
    __shared__ short8 Ahi[2][GPC];      // 2 x 8 KiB
    __shared__ short8 Alo[2][GPC];      // 2 x 8 KiB
    __shared__ float4 e2L[K / 4];       // 2 KiB
    __shared__ float4 zt[PPB * ZSTR];   // 17.4 KiB padded z-tile
    __shared__ int    bidx_s[PPB];

    const int tid = threadIdx.x;
    const int w   = tid >> 6;         // wave -> owns point-tile w
    const int l   = tid & 63;
    const int col = l & 15;           // point within tile
    const int kg  = l >> 4;           // k-group / code-row group

    const float4* zf4 = reinterpret_cast<const float4*>(z);
    const float4* ef4 = reinterpret_cast<const float4*>(emb);
    float4*       of4 = reinterpret_cast<float4*>(out);

    const int base = blockIdx.x * PPB;

    // stage chunk c (64 codes, hi+lo) into buffer b: pure linear copy,
    // source already in LDS-image (swizzled) order.
    auto stage = [&](int c, int b) {
        const short8* sH = wsHi + c * GPC;
        const short8* sL = wsLo + c * GPC;
        #pragma unroll
        for (int i = 0; i < 2; ++i) {
            const int f = i * 256 + tid;
            __builtin_amdgcn_global_load_lds(AS_G(sH + f),
                                             AS_L(&Ahi[b][f]), 16, 0, 0);
            __builtin_amdgcn_global_load_lds(AS_G(sL + f),
                                             AS_L(&Alo[b][f]), 16, 0, 0);
        }
    };

    stage(0, 0);   // in flight during z-tile staging
    if (tid < K / 4)   // e2 -> LDS, lane-linear 16B granules
        __builtin_amdgcn_global_load_lds(AS_G(e2 + tid * 4),
                                         AS_L(&e2L[tid]), 16, 0, 0);

    // ---- z-tile: COALESCED global loads -> padded LDS rows ----
    // wave-instruction reads 64 consecutive float4 (1KB contiguous).
    #pragma unroll
    for (int i = 0; i < (PPB * 16) / BLOCK; ++i) {   // 4 iters
        const int idx = i * BLOCK + tid;             // 0..1023
        const float4 v = zf4[base * 16 + idx];
        zt[(idx >> 4) * ZSTR + (idx & 15)] = v;
    }

    __syncthreads();   // z-tile + chunk 0 + e2L resident

    const int zrow = (w * 16 + col) * ZSTR;   // this lane's point row in zt

    // ---- x2 from LDS, exact sequential unfused chain (same values/order) ----
    float x2v = 0.0f;
    {
        #pragma clang fp contract(off)
        #pragma unroll
        for (int i = 0; i < 16; ++i) {
            float4 q = zt[zrow + i];
            x2v = x2v + q.x * q.x;
            x2v = x2v + q.y * q.y;
            x2v = x2v + q.z * q.z;
            x2v = x2v + q.w * q.w;
        }
    }

    // ---- B-frags from LDS (identical build chain to R13) ----
    short8 bh[2], bl[2];
    #pragma unroll
    for (int kt = 0; kt < 2; ++kt) {
        const float4 va = zt[zrow + kt * 8 + kg * 2];
        const float4 vb = zt[zrow + kt * 8 + kg * 2 + 1];
        const float xs[8] = {va.x, va.y, va.z, va.w, vb.x, vb.y, vb.z, vb.w};
        #pragma unroll
        for (int e = 0; e < 8; ++e) {
            const unsigned short h = bf16_rne(xs[e]);
            const float r = xs[e] - bf16_f32(h);   // exact
            bh[kt][e] = (short)h;
            bl[kt][e] = (short)bf16_rne(r);
        }
    }

    // Independent argmin slot per tile-position (R13 semantics).
    float bv0 = INFINITY, bv1 = INFINITY, bv2 = INFINITY, bv3 = INFINITY;
    int   ix0 = 0, ix1 = 0, ix2 = 0, ix3 = 0;
    int   b = 0;

    for (int c = 0; c < NCHUNK; ++c) {
        if (c + 1 < NCHUNK) stage(c + 1, b ^ 1);

        #pragma unroll
        for (int t = 0; t < 4; ++t) {
            // swizzled A slots: code_local = t*16+col, sidx = (kt*4+kg)^(col&7)
            const int slot0 = ((t * 16 + col) << 3) | (kg ^ (col & 7)); // kt=0
            const short8 ah0 = Ahi[b][slot0];
            const short8 ah1 = Ahi[b][slot0 ^ 4];                        // kt=1
            const short8 al0 = Alo[b][slot0];
            const short8 al1 = Alo[b][slot0 ^ 4];

            f32x4 acc = {0.f, 0.f, 0.f, 0.f};
            // same term order as R5/R7/R8/R12/R13: per kt {al*bh, ah*bl, ah*bh}
            acc = __builtin_amdgcn_mfma_f32_16x16x32_bf16(al0, bh[0], acc, 0, 0, 0);
            acc = __builtin_amdgcn_mfma_f32_16x16x32_bf16(ah0, bl[0], acc, 0, 0, 0);
            acc = __builtin_amdgcn_mfma_f32_16x16x32_bf16(ah0, bh[0], acc, 0, 0, 0);
            acc = __builtin_amdgcn_mfma_f32_16x16x32_bf16(al1, bh[1], acc, 0, 0, 0);
            acc = __builtin_amdgcn_mfma_f32_16x16x32_bf16(ah1, bl[1], acc, 0, 0, 0);
            acc = __builtin_amdgcn_mfma_f32_16x16x32_bf16(ah1, bh[1], acc, 0, 0, 0);

            const int   kbase = c * CHUNK + t * 16 + kg * 4;
            const float4 e2v  = e2L[kbase >> 2];   // broadcast ds_read
            const float d0 = (x2v - 2.0f * acc[0]) + e2v.x;
            const float d1 = (x2v - 2.0f * acc[1]) + e2v.y;
            const float d2 = (x2v - 2.0f * acc[2]) + e2v.z;
            const float d3 = (x2v - 2.0f * acc[3]) + e2v.w;

            float mv01 = d0; int mi01 = kbase + 0;
            if (d1 < mv01) { mv01 = d1; mi01 = kbase + 1; }
            float mv23 = d2; int mi23 = kbase + 2;
            if (d3 < mv23) { mv23 = d3; mi23 = kbase + 3; }
            float mv = mv01; int mi = mi01;
            if (mv23 < mv) { mv = mv23; mi = mi23; }
            if (t == 0) { if (mv < bv0) { bv0 = mv; ix0 = mi; } }
            if (t == 1) { if (mv < bv1) { bv1 = mv; ix1 = mi; } }
            if (t == 2) { if (mv < bv2) { bv2 = mv; ix2 = mi; } }
            if (t == 3) { if (mv < bv3) { bv3 = mv; ix3 = mi; } }
        }
        __syncthreads();   // drains stage vmcnt + all waves done with buf b
        b ^= 1;
    }

    // merge the 4 slots: lexicographic (val, idx) == global first-index
    float best = bv0; int bi = ix0;
    if (bv1 < best || (bv1 == best && ix1 < bi)) { best = bv1; bi = ix1; }
    if (bv2 < best || (bv2 == best && ix2 < bi)) { best = bv2; bi = ix2; }
    if (bv3 < best || (bv3 == best && ix3 < bi)) { best = bv3; bi = ix3; }

    // combine 4 kg-groups (lanes sharing a column): lexicographic (dist, idx)
    #pragma unroll
    for (int off = 16; off < 64; off <<= 1) {
        const float ov = __shfl_xor(best, off);
        const int   oi = __shfl_xor(bi,   off);
        if (ov < best || (ov == best && oi < bi)) { best = ov; bi = oi; }
    }
    if (l < 16) bidx_s[w * 16 + col] = bi;
    __syncthreads();

    // dense epilogue: q gathered from global, x from the LDS z-tile
    // (bit-identical copies); lane-linear float4 stores.
    #pragma unroll
    for (int i = 0; i < (PPB * 16) / BLOCK; ++i) {   // 4 iters
        const int idx = i * BLOCK + tid;
        const int p   = idx >> 4;
        const int j   = idx & 15;
        const float4 q = ef4[bidx_s[p] * 16 + j];
        const float4 x = zt[p * ZSTR + j];
        float4 o;
        o.x = (q.x + x.x) - x.x;
        o.y = (q.y + x.y) - x.y;
        o.z = (q.z + x.z) - x.z;
        o.w = (q.w + x.w) - x.w;
        of4[(base + p) * 16 + j] = o;
    }
}

extern "C" void kernel_launch(void* const* d_in, const int* in_sizes, int n_in,
                              void* d_out, int out_size, void* d_ws, size_t ws_size,
                              hipStream_t stream) {
    const float* z   = (const float*)d_in[0];
    const float* emb = (const float*)d_in[1];
    float* out = (float*)d_out;

    // ws: e2 f32[512] (2KB) | wsHi short8[4096] (64KB) | wsLo short8[4096] (64KB)
    float*  e2   = (float*)d_ws;
    short8* wsHi = (short8*)((char*)d_ws + 2048);
    short8* wsLo = (short8*)((char*)d_ws + 2048 + 65536);

    prep_emb<<<16, 256, 0, stream>>>(emb, e2, wsHi, wsLo);
    vq_mfma<<<NPTS / PPB, BLOCK, 0, stream>>>(z, emb, e2, wsHi, wsLo, out);
}

// Round 19
// 31.138 us; speedup vs baseline: 1.9247x; 1.0452x over previous
//
#include <hip/hip_runtime.h>
#include <math.h>

// st_VQEmbedding via LDS-staged MFMA GEMM.
// R19 = R8 geometry (PPB=128, 2 point-tiles/wave: each A-read feeds 2x MFMA)
//     + R18 coalesced z-tile in LDS (the -4.4us win)
//     + R13 independent argmin slots (8 = 2 points x 4 tile-positions).
// dist = (x2 - 2*dot) + e2, dot via bf16 2-term split MFMA (al*bh + ah*bl +
// ah*bh, fp32 accum) -- bit-identical chains/term order/tie-break to
// R5/R7/R8/R12/R13/R18 (all passed absmax 0.0).

constexpr int K      = 512;
constexpr int D      = 64;
constexpr int NPTS   = 16 * 4096;    // 65536
constexpr int BLOCK  = 256;
constexpr int PPB    = 128;          // points per block (4 waves x 32)
constexpr int CHUNK  = 64;           // codes per LDS chunk
constexpr int NCHUNK = K / CHUNK;    // 8
constexpr int GPC    = CHUNK * 8;    // 512 16B-granules per chunk per array
constexpr int ZSTR   = 17;           // z-tile row stride in float4 (272 B)

typedef __attribute__((ext_vector_type(8))) short  short8;
typedef __attribute__((ext_vector_type(4))) float  f32x4;

#define AS_G (const __attribute__((address_space(1))) void*)
#define AS_L (__attribute__((address_space(3))) void*)

__device__ inline unsigned short bf16_rne(float f) {
    unsigned u = __builtin_bit_cast(unsigned, f);
    u += 0x7fffu + ((u >> 16) & 1u);
    return (unsigned short)(u >> 16);
}
__device__ inline float bf16_f32(unsigned short h) {
    unsigned u = (unsigned)h << 16;
    return __builtin_bit_cast(float, u);
}

// ---- prep: e2 (exact chain) + bf16 hi/lo split, written pre-swizzled ------
// ws granule index = (k>>6)*GPC + (k&63)*8 + (s ^ (k&7))   [identical to R13]
__global__ void prep_emb(const float* __restrict__ emb,
                         float* __restrict__ e2,
                         short8* __restrict__ wsHi,
                         short8* __restrict__ wsLo)
{
    const int gid = blockIdx.x * 256 + threadIdx.x;   // 0..4095
    const int k = gid >> 3;
    const int s = gid & 7;

    const float4* row = reinterpret_cast<const float4*>(emb + k * D);
    float v[64];
    #pragma unroll
    for (int i = 0; i < 16; ++i) {
        float4 q = row[i];
        v[4*i+0] = q.x; v[4*i+1] = q.y; v[4*i+2] = q.z; v[4*i+3] = q.w;
    }
    if (s == 0) {   // exact sequential unfused e2 (same chain as R1-R18)
        float acc = 0.0f;
        {
            #pragma clang fp contract(off)
            #pragma unroll
            for (int d = 0; d < 64; ++d) acc = acc + v[d] * v[d];
        }
        e2[k] = acc;
    }
    short8 hi, lo;
    #pragma unroll
    for (int e = 0; e < 8; ++e) {
        const float f = v[s * 8 + e];
        const unsigned short h = bf16_rne(f);
        const float r = f - bf16_f32(h);          // exact (Sterbenz)
        hi[e] = (short)h;
        lo[e] = (short)bf16_rne(r);
    }
    const int slot = (k >> 6) * GPC + (k & 63) * 8 + (s ^ (k & 7));
    wsHi[slot] = hi;
    wsLo[slot] = lo;
}

// ---- main: LDS-staged MFMA argmin + gather ---------------------------------
__global__ __launch_bounds__(BLOCK, 2)
void vq_mfma(const float* __restrict__ z,
             const float* __restrict__ emb,
             const float* __restrict__ e2,
             const short8* __restrict__ wsHi,
             const short8* __restrict__ wsLo,
             float* __restrict__ out)
{
    __shared__ short8 Ahi[2][GPC];      // 2 x 8 KiB
    __shared__ short8 Alo[2][GPC];      // 2 x 8 KiB
    __shared__ float4 e2L[K / 4];       // 2 KiB
    __shared__ float4 zt[PPB * ZSTR];   // 34.8 KiB padded z-tile
    __shared__ int    bidx_s[PPB];

    const int tid = threadIdx.x;
    const int w   = tid >> 6;         // wave -> owns point-tiles 2w, 2w+1
    const int l   = tid & 63;
    const int col = l & 15;           // point within tile / code within tile
    const int kg  = l >> 4;           // k-group / code-row group

    const float4* zf4 = reinterpret_cast<const float4*>(z);
    const float4* ef4 = reinterpret_cast<const float4*>(emb);
    float4*       of4 = reinterpret_cast<float4*>(out);

    const int base = blockIdx.x * PPB;

    // stage chunk c (64 codes, hi+lo) into buffer b: pure linear copy,
    // source already in LDS-image (swizzled) order.
    auto stage = [&](int c, int b) {
        const short8* sH = wsHi + c * GPC;
        const short8* sL = wsLo + c * GPC;
        #pragma unroll
        for (int i = 0; i < 2; ++i) {
            const int f = i * 256 + tid;
            __builtin_amdgcn_global_load_lds(AS_G(sH + f),
                                             AS_L(&Ahi[b][f]), 16, 0, 0);
            __builtin_amdgcn_global_load_lds(AS_G(sL + f),
                                             AS_L(&Alo[b][f]), 16, 0, 0);
        }
    };

    stage(0, 0);   // in flight during z-tile staging
    if (tid < K / 4)   // e2 -> LDS, lane-linear 16B granules
        __builtin_amdgcn_global_load_lds(AS_G(e2 + tid * 4),
                                         AS_L(&e2L[tid]), 16, 0, 0);

    // ---- z-tile: COALESCED global loads -> padded LDS rows (R18 win) ----
    #pragma unroll
    for (int i = 0; i < (PPB * 16) / BLOCK; ++i) {   // 8 iters
        const int idx = i * BLOCK + tid;             // 0..2047
        const float4 v = zf4[base * 16 + idx];
        zt[(idx >> 4) * ZSTR + (idx & 15)] = v;
    }

    __syncthreads();   // z-tile + chunk 0 + e2L resident

    // ---- per-point x2 (from LDS) + B-frags for 2 point-tiles ----
    float  x2v[2];
    short8 bh[2][2], bl[2][2];
    #pragma unroll
    for (int p = 0; p < 2; ++p) {
        const int zrow = (w * 32 + p * 16 + col) * ZSTR;
        float s = 0.0f;
        {
            #pragma clang fp contract(off)
            #pragma unroll
            for (int i = 0; i < 16; ++i) {
                float4 q = zt[zrow + i];
                s = s + q.x * q.x;
                s = s + q.y * q.y;
                s = s + q.z * q.z;
                s = s + q.w * q.w;
            }
        }
        x2v[p] = s;
        #pragma unroll
        for (int kt = 0; kt < 2; ++kt) {
            const float4 va = zt[zrow + kt * 8 + kg * 2];
            const float4 vb = zt[zrow + kt * 8 + kg * 2 + 1];
            const float xs[8] = {va.x, va.y, va.z, va.w, vb.x, vb.y, vb.z, vb.w};
            #pragma unroll
            for (int e = 0; e < 8; ++e) {
                const unsigned short h = bf16_rne(xs[e]);
                const float r = xs[e] - bf16_f32(h);   // exact
                bh[p][kt][e] = (short)h;
                bl[p][kt][e] = (short)bf16_rne(r);
            }
        }
    }

    // 8 independent argmin slots: (p,t) named scalars (R13 semantics).
    float bv00 = INFINITY, bv01 = INFINITY, bv02 = INFINITY, bv03 = INFINITY;
    float bv10 = INFINITY, bv11 = INFINITY, bv12 = INFINITY, bv13 = INFINITY;
    int   ix00 = 0, ix01 = 0, ix02 = 0, ix03 = 0;
    int   ix10 = 0, ix11 = 0, ix12 = 0, ix13 = 0;
    int   b = 0;

    for (int c = 0; c < NCHUNK; ++c) {
        if (c + 1 < NCHUNK) stage(c + 1, b ^ 1);

        #pragma unroll
        for (int t = 0; t < 4; ++t) {
            // swizzled A slots: code_local = t*16+col, sidx = (kt*4+kg)^(col&7)
            const int slot0 = ((t * 16 + col) << 3) | (kg ^ (col & 7)); // kt=0
            const short8 ah0 = Ahi[b][slot0];
            const short8 ah1 = Ahi[b][slot0 ^ 4];                        // kt=1
            const short8 al0 = Alo[b][slot0];
            const short8 al1 = Alo[b][slot0 ^ 4];

            f32x4 acc0 = {0.f, 0.f, 0.f, 0.f};
            f32x4 acc1 = {0.f, 0.f, 0.f, 0.f};
            // same term order as R5/R7/R8: per kt {al*bh, ah*bl, ah*bh}
            acc0 = __builtin_amdgcn_mfma_f32_16x16x32_bf16(al0, bh[0][0], acc0, 0, 0, 0);
            acc0 = __builtin_amdgcn_mfma_f32_16x16x32_bf16(ah0, bl[0][0], acc0, 0, 0, 0);
            acc0 = __builtin_amdgcn_mfma_f32_16x16x32_bf16(ah0, bh[0][0], acc0, 0, 0, 0);
            acc0 = __builtin_amdgcn_mfma_f32_16x16x32_bf16(al1, bh[0][1], acc0, 0, 0, 0);
            acc0 = __builtin_amdgcn_mfma_f32_16x16x32_bf16(ah1, bl[0][1], acc0, 0, 0, 0);
            acc0 = __builtin_amdgcn_mfma_f32_16x16x32_bf16(ah1, bh[0][1], acc0, 0, 0, 0);

            acc1 = __builtin_amdgcn_mfma_f32_16x16x32_bf16(al0, bh[1][0], acc1, 0, 0, 0);
            acc1 = __builtin_amdgcn_mfma_f32_16x16x32_bf16(ah0, bl[1][0], acc1, 0, 0, 0);
            acc1 = __builtin_amdgcn_mfma_f32_16x16x32_bf16(ah0, bh[1][0], acc1, 0, 0, 0);
            acc1 = __builtin_amdgcn_mfma_f32_16x16x32_bf16(al1, bh[1][1], acc1, 0, 0, 0);
            acc1 = __builtin_amdgcn_mfma_f32_16x16x32_bf16(ah1, bl[1][1], acc1, 0, 0, 0);
            acc1 = __builtin_amdgcn_mfma_f32_16x16x32_bf16(ah1, bh[1][1], acc1, 0, 0, 0);

            const int   kbase = c * CHUNK + t * 16 + kg * 4;
            const float4 e2v  = e2L[kbase >> 2];   // broadcast ds_read

            // point-tile 0: tree argmin + slot(p=0,t) update
            {
                const float d0 = (x2v[0] - 2.0f * acc0[0]) + e2v.x;
                const float d1 = (x2v[0] - 2.0f * acc0[1]) + e2v.y;
                const float d2 = (x2v[0] - 2.0f * acc0[2]) + e2v.z;
                const float d3 = (x2v[0] - 2.0f * acc0[3]) + e2v.w;
                float mv01 = d0; int mi01 = kbase + 0;
                if (d1 < mv01) { mv01 = d1; mi01 = kbase + 1; }
                float mv23 = d2; int mi23 = kbase + 2;
                if (d3 < mv23) { mv23 = d3; mi23 = kbase + 3; }
                float mv = mv01; int mi = mi01;
                if (mv23 < mv) { mv = mv23; mi = mi23; }
                if (t == 0) { if (mv < bv00) { bv00 = mv; ix00 = mi; } }
                if (t == 1) { if (mv < bv01) { bv01 = mv; ix01 = mi; } }
                if (t == 2) { if (mv < bv02) { bv02 = mv; ix02 = mi; } }
                if (t == 3) { if (mv < bv03) { bv03 = mv; ix03 = mi; } }
            }
            // point-tile 1: tree argmin + slot(p=1,t) update
            {
                const float d0 = (x2v[1] - 2.0f * acc1[0]) + e2v.x;
                const float d1 = (x2v[1] - 2.0f * acc1[1]) + e2v.y;
                const float d2 = (x2v[1] - 2.0f * acc1[2]) + e2v.z;
                const float d3 = (x2v[1] - 2.0f * acc1[3]) + e2v.w;
                float mv01 = d0; int mi01 = kbase + 0;
                if (d1 < mv01) { mv01 = d1; mi01 = kbase + 1; }
                float mv23 = d2; int mi23 = kbase + 2;
                if (d3 < mv23) { mv23 = d3; mi23 = kbase + 3; }
                float mv = mv01; int mi = mi01;
                if (mv23 < mv) { mv = mv23; mi = mi23; }
                if (t == 0) { if (mv < bv10) { bv10 = mv; ix10 = mi; } }
                if (t == 1) { if (mv < bv11) { bv11 = mv; ix11 = mi; } }
                if (t == 2) { if (mv < bv12) { bv12 = mv; ix12 = mi; } }
                if (t == 3) { if (mv < bv13) { bv13 = mv; ix13 = mi; } }
            }
        }
        __syncthreads();   // drains stage vmcnt + all waves done with buf b
        b ^= 1;
    }

    // merge slots per point: lexicographic (val, idx) == global first-index
    float best0 = bv00; int bi0 = ix00;
    if (bv01 < best0 || (bv01 == best0 && ix01 < bi0)) { best0 = bv01; bi0 = ix01; }
    if (bv02 < best0 || (bv02 == best0 && ix02 < bi0)) { best0 = bv02; bi0 = ix02; }
    if (bv03 < best0 || (bv03 == best0 && ix03 < bi0)) { best0 = bv03; bi0 = ix03; }
    float best1 = bv10; int bi1 = ix10;
    if (bv11 < best1 || (bv11 == best1 && ix11 < bi1)) { best1 = bv11; bi1 = ix11; }
    if (bv12 < best1 || (bv12 == best1 && ix12 < bi1)) { best1 = bv12; bi1 = ix12; }
    if (bv13 < best1 || (bv13 == best1 && ix13 < bi1)) { best1 = bv13; bi1 = ix13; }

    // combine 4 kg-groups (lanes sharing a column): lexicographic (dist, idx)
    #pragma unroll
    for (int off = 16; off < 64; off <<= 1) {
        float ov = __shfl_xor(best0, off);
        int   oi = __shfl_xor(bi0,   off);
        if (ov < best0 || (ov == best0 && oi < bi0)) { best0 = ov; bi0 = oi; }
        ov = __shfl_xor(best1, off);
        oi = __shfl_xor(bi1,   off);
        if (ov < best1 || (ov == best1 && oi < bi1)) { best1 = ov; bi1 = oi; }
    }
    if (l < 16) {
        bidx_s[w * 32 + col]      = bi0;
        bidx_s[w * 32 + 16 + col] = bi1;
    }
    __syncthreads();

    // dense epilogue: q from global, x from LDS z-tile; lane-linear stores
    #pragma unroll
    for (int i = 0; i < (PPB * 16) / BLOCK; ++i) {   // 8 iters
        const int idx = i * BLOCK + tid;
        const int p   = idx >> 4;
        const int j   = idx & 15;
        const float4 q = ef4[bidx_s[p] * 16 + j];
        const float4 x = zt[p * ZSTR + j];
        float4 o;
        o.x = (q.x + x.x) - x.x;
        o.y = (q.y + x.y) - x.y;
        o.z = (q.z + x.z) - x.z;
        o.w = (q.w + x.w) - x.w;
        of4[(base + p) * 16 + j] = o;
    }
}

extern "C" void kernel_launch(void* const* d_in, const int* in_sizes, int n_in,
                              void* d_out, int out_size, void* d_ws, size_t ws_size,
                              hipStream_t stream) {
    const float* z   = (const float*)d_in[0];
    const float* emb = (const float*)d_in[1];
    float* out = (float*)d_out;

    // ws: e2 f32[512] (2KB) | wsHi short8[4096] (64KB) | wsLo short8[4096] (64KB)
    float*  e2   = (float*)d_ws;
    short8* wsHi = (short8*)((char*)d_ws + 2048);
    short8* wsLo = (short8*)((char*)d_ws + 2048 + 65536);

    prep_emb<<<16, 256, 0, stream>>>(emb, e2, wsHi, wsLo);
    vq_mfma<<<NPTS / PPB, BLOCK, 0, stream>>>(z, emb, e2, wsHi, wsLo, out);
}